// Round 1
// baseline (428.297 us; speedup 1.0000x reference)
//
#include <hip/hip_runtime.h>

// SubsetSampler: out0 = x (f32 passthrough), out1 = float(mask | (l >= cutoff)),
// cutoff_b = min(ceil(0.7 * count_false(mask[b,:])), L-1).  B=8192, L=4096.
//
// R5: one WAVE per row (64 lanes x 64 elems). Removes LDS + both __syncthreads
// + cross-wave reduce of the block-per-row version: the False-count is a pure
// wave-local shfl_xor butterfly, mask bits live in a per-lane uint64, and all
// 32 memory ops (16 mask dwords + 16 x float4) are in flight before any wait.
// Harness-fixed: ~334 us poison fills. Controllable floor ~= 436 MB @ 6.5 TB/s
// = 67 us + detect ~4 us.

#define L_DIM 4096
#define SUBSET_RATE 0.7f

typedef float        f32x4 __attribute__((ext_vector_type(4)));
typedef unsigned int u32x4 __attribute__((ext_vector_type(4)));

// ---- mask-storage detection (1 block, 16 KB read, ~4 us) --------------------
// byte bools: padding runs of 0x01 -> some word > 1 in the first 4096 words.
// f32 bools: word 0x3f800000. int32 bools: words 0/1 only. Word-sized layouts
// (int32/f32) share the decode path (nonzero == True). mode: 1=bytes, 0=words.
__global__ void detect_mode_kernel(const unsigned int* __restrict__ m,
                                   int* __restrict__ mode) {
    __shared__ int any_gt1, any_f32;
    if (threadIdx.x == 0) { any_gt1 = 0; any_f32 = 0; }
    __syncthreads();
    int lgt1 = 0, lf32 = 0;
    for (int i = threadIdx.x; i < L_DIM; i += blockDim.x) {
        unsigned int w = m[i];
        if (w == 0x3f800000u)      lf32 = 1;
        else if (w > 1u)           lgt1 = 1;
    }
    if (lgt1) any_gt1 = 1;   // benign same-value race
    if (lf32) any_f32 = 1;
    __syncthreads();
    if (threadIdx.x == 0)
        *mode = (any_f32 ? 0 : (any_gt1 ? 1 : 0));
}

// ---- main kernel ------------------------------------------------------------
// One wave per row. Lane l owns float4 chunks c = l + 64*m, m=0..15 (elements
// 4l+256m .. 4l+256m+3) -> every wave memory instr spans contiguous 1 KB.
// No LDS, no __syncthreads: reduction is wave-local.
__global__ __launch_bounds__(256, 4)
void subset_kernel(const float* __restrict__ x,
                   const void* __restrict__ mask,
                   const int* __restrict__ mode_p,
                   float* __restrict__ out_x,
                   float* __restrict__ out_mask,
                   int B) {
    const int wave = threadIdx.x >> 6;
    const int lane = threadIdx.x & 63;
    const int row  = blockIdx.x * 4 + wave;
    if (row >= B) return;

    const int mode = *mode_p;                 // wave-uniform scalar load
    const size_t rowoff = (size_t)row * L_DIM;

    const f32x4* xr  = (const f32x4*)(x        + rowoff);
    f32x4*       oxr = (f32x4*)      (out_x    + rowoff);
    f32x4*       omr = (f32x4*)      (out_mask + rowoff);

    // bit (4m+j) = mask value of element 4*lane + 256*m + j
    unsigned long long bits = 0ull;
    f32x4 xv[16];

    if (mode == 1) {
        // 1-byte bools: dword at word index c covers chunk c's 4 elements.
        const unsigned int* mp =
            (const unsigned int*)((const unsigned char*)mask + rowoff);
        unsigned int mw[16];
        #pragma unroll
        for (int m = 0; m < 16; ++m)          // mask loads first (reduce needs them)
            mw[m] = __builtin_nontemporal_load(&mp[lane + 64 * m]);
        #pragma unroll
        for (int m = 0; m < 16; ++m)          // x loads overlap; consumed last
            xv[m] = __builtin_nontemporal_load(&xr[lane + 64 * m]);
        #pragma unroll
        for (int m = 0; m < 16; ++m) {
            // per-byte nonzero -> bits {0,8,16,24}, then pack to low nibble
            unsigned int w  = mw[m];
            unsigned int nz = w | (w >> 4);
            nz |= nz >> 2;
            nz |= nz >> 1;
            nz &= 0x01010101u;
            unsigned int nib = (nz * 0x01020408u) >> 24;  // bit j = byte j != 0
            bits |= (unsigned long long)(nib & 0xFu) << (4 * m);
        }
    } else {
        // 4-byte elements (int32 0/1 or f32 bits): nonzero word == True.
        const u32x4* mp = (const u32x4*)((const unsigned int*)mask + rowoff);
        #pragma unroll
        for (int m = 0; m < 16; ++m)
            xv[m] = __builtin_nontemporal_load(&xr[lane + 64 * m]);
        #pragma unroll
        for (int m = 0; m < 16; ++m) {
            u32x4 w = __builtin_nontemporal_load(&mp[lane + 64 * m]);
            unsigned int nib = (w.x ? 1u : 0u) | (w.y ? 2u : 0u)
                             | (w.z ? 4u : 0u) | (w.w ? 8u : 0u);
            bits |= (unsigned long long)nib << (4 * m);
        }
    }

    // ---- wave-local False count + butterfly (all lanes get the total) ----
    int zeros = 64 - __popcll(bits);
    #pragma unroll
    for (int off = 1; off < 64; off <<= 1)
        zeros += __shfl_xor(zeros, off, 64);

    // exact match to jnp: f32 multiply (one rounding), f32 ceil, min
    const int cutoff = min((int)ceilf((float)zeros * SUBSET_RATE), L_DIM - 1);

    // ---- drain x, then computed mask (no barriers anywhere) ----
    #pragma unroll
    for (int m = 0; m < 16; ++m)
        __builtin_nontemporal_store(xv[m], &oxr[lane + 64 * m]);

    #pragma unroll
    for (int m = 0; m < 16; ++m) {
        const int i0 = 4 * lane + 256 * m;
        f32x4 mv;
        mv.x = (((bits >> (4 * m + 0)) & 1ull) || (i0 + 0 >= cutoff)) ? 1.0f : 0.0f;
        mv.y = (((bits >> (4 * m + 1)) & 1ull) || (i0 + 1 >= cutoff)) ? 1.0f : 0.0f;
        mv.z = (((bits >> (4 * m + 2)) & 1ull) || (i0 + 2 >= cutoff)) ? 1.0f : 0.0f;
        mv.w = (((bits >> (4 * m + 3)) & 1ull) || (i0 + 3 >= cutoff)) ? 1.0f : 0.0f;
        __builtin_nontemporal_store(mv, &omr[lane + 64 * m]);
    }
}

extern "C" void kernel_launch(void* const* d_in, const int* in_sizes, int n_in,
                              void* d_out, int out_size, void* d_ws, size_t ws_size,
                              hipStream_t stream) {
    const float* x    = (const float*)d_in[0];
    const void*  mask = d_in[1];
    const int B = in_sizes[0] / L_DIM;            // 8192

    float* out_x    = (float*)d_out;              // first B*L floats
    float* out_mask = out_x + (size_t)B * L_DIM;  // next B*L floats (0.0/1.0)
    int*   mode     = (int*)d_ws;                 // rewritten every call

    detect_mode_kernel<<<1, 256, 0, stream>>>((const unsigned int*)mask, mode);
    subset_kernel<<<(B + 3) / 4, 256, 0, stream>>>(x, mask, mode, out_x, out_mask, B);
}